// Round 4
// baseline (6436.955 us; speedup 1.0000x reference)
//
#include <hip/hip_runtime.h>

// RetinaNet 3D head: 2 heads (cls, reg) x 4 pyramid levels.
// Interior levels: S = 32,16,8,4 ; voxels 32768,4096,512,64 ; total 37440.
// Activations live in ZERO-PADDED per-channel volumes (S+2)^3; activations
// stored RAW (pre-norm); InstanceNorm+PReLU is fused into the LDS staging
// read of the NEXT conv layer using stats accumulated by the previous one.
// Padded vols: 39304, 5832, 1000, 216 ; per-channel total 46352.

static constexpr int CLS_TOTAL  = 673920;            // 18 * 37440
static constexpr int TOTPADV    = 46352;
static constexpr size_t HSTRIDE_P = (size_t)64 * TOTPADV;
static constexpr int PADIN_SZ   = 36 * TOTPADV;      // 1,668,672
static constexpr int HALO       = 600;               // 10*10*6

// sb in [0,147): l0:128 tiles, l1:16, l2:2, l3:1. Tile = 8x8x4 interior.
__device__ __forceinline__ void decompose(int sb, int& lvl, int& S, int& P,
                                          int& vol, int& cvol,
                                          int& x0, int& y0, int& z0)
{
    int t;
    if (sb < 128)      { lvl = 0; t = sb; }
    else if (sb < 144) { lvl = 1; t = sb - 128; }
    else if (sb < 146) { lvl = 2; t = sb - 144; }
    else               { lvl = 3; t = 0; }
    const int ls = 5 - lvl;
    S = 1 << ls; P = S + 2;
    vol  = (lvl == 0) ? 39304 : (lvl == 1) ? 5832 : (lvl == 2) ? 1000 : 216;
    cvol = (lvl == 0) ? 0     : (lvl == 1) ? 39304 : (lvl == 2) ? 45136 : 46136;
    const int ntx = (S >= 8) ? (S >> 3) : 1;
    x0 = (t % ntx) * 8;
    const int rem = t / ntx;
    y0 = (rem % ntx) * 8;
    z0 = (rem / ntx) * 4;
}

// ---------------------------------------------------------------------------
// Copy unpadded inputs p0..p3 (36 ch) into padded padin interiors.
// ---------------------------------------------------------------------------
__global__ __launch_bounds__(256) void padcopy_kernel(
    const float* __restrict__ p0, const float* __restrict__ p1,
    const float* __restrict__ p2, const float* __restrict__ p3,
    float* __restrict__ padin)
{
    const int e = blockIdx.x * 256 + (int)threadIdx.x;
    int lvl;
    if (e < 1179648)      lvl = 0;
    else if (e < 1327104) lvl = 1;
    else if (e < 1345536) lvl = 2;
    else                  lvl = 3;
    const int ce   = (lvl == 0) ? 0 : (lvl == 1) ? 1179648 : (lvl == 2) ? 1327104 : 1345536;
    const int ls   = 5 - lvl, S = 1 << ls, P = S + 2;
    const int nvox = 1 << (3 * ls);
    const int vol  = (lvl == 0) ? 39304 : (lvl == 1) ? 5832 : (lvl == 2) ? 1000 : 216;
    const int cvol = (lvl == 0) ? 0     : (lvl == 1) ? 39304 : (lvl == 2) ? 45136 : 46136;
    const int ch   = (e - ce) >> (3 * ls);
    const int vox  = (e - ce) & (nvox - 1);
    const int x = vox & (S - 1), y = (vox >> ls) & (S - 1), z = vox >> (2 * ls);
    const float* src = (lvl == 0) ? p0 : (lvl == 1) ? p1 : (lvl == 2) ? p2 : p3;
    padin[36 * cvol + ch * vol + ((z + 1) * P + (y + 1)) * P + (x + 1)] =
        src[ch * nvox + vox];
}

// ---------------------------------------------------------------------------
// Conv3d 3x3x3 + bias with LDS-staged input tile.  Optionally applies
// InstanceNorm+PReLU (prev layer stats) to the staged values.  Accumulates
// this layer's sum/sumsq stats.  Grid: (147, 64/NCO, 2 heads), block 256.
// ---------------------------------------------------------------------------
template<int CIN, int NCO, bool NORM>
__global__ __launch_bounds__(256) void conv_tile_kernel(
    const float* __restrict__ src, const size_t head_stride,
    const float* __restrict__ w_cls, const float* __restrict__ w_reg,
    const float* __restrict__ b_cls, const float* __restrict__ b_reg,
    const float* __restrict__ prev_stats,
    const float* __restrict__ a_cls, const float* __restrict__ a_reg,
    const int prev_layer,
    float* __restrict__ dst, float* __restrict__ stats)
{
    __shared__ float lds[2][HALO];
    const int tid  = threadIdx.x;
    const int head = blockIdx.z;
    const int co0  = blockIdx.y * NCO;

    int lvl, S, P, vol, cvol, x0, y0, z0;
    decompose(blockIdx.x, lvl, S, P, vol, cvol, x0, y0, z0);

    const float* in = src + head * head_stride + (size_t)CIN * cvol;
    const float* w  = head ? w_reg : w_cls;
    const float* b  = head ? b_reg : b_cls;
    const float alpha = NORM ? (head ? a_reg : a_cls)[prev_layer] : 0.0f;
    const float inv_n = 1.0f / (float)(1 << (3 * (5 - lvl)));
    const float* pst = NORM ? (prev_stats + (size_t)((head * 4 + lvl) * 64) * 2) : nullptr;

    // staging slots: tid, tid+256, tid+512 (<600)
    int soff0, soff1, soff2; float ok0, ok1, ok2;
    {
        auto mk = [&](int i, int& so, float& ok) {
            const int zz = i / 100, rr = i - zz * 100, yy = rr / 10, xx = rr - yy * 10;
            so = ((z0 + zz) * P + (y0 + yy)) * P + (x0 + xx);
            const int gx = x0 + xx - 1, gy = y0 + yy - 1, gz = z0 + zz - 1;
            ok = ((unsigned)gx < (unsigned)S && (unsigned)gy < (unsigned)S &&
                  (unsigned)gz < (unsigned)S) ? 1.0f : 0.0f;
        };
        mk(tid, soff0, ok0);
        mk(tid + 256, soff1, ok1);
        mk(tid < 88 ? tid + 512 : 0, soff2, ok2);
        if (tid >= 88) ok2 = 0.0f;
    }

    const int tx = tid & 7, ty = (tid >> 3) & 7, tz = tid >> 6;
    const int lbase = (tz * 10 + ty) * 10 + tx;      // center at +1 offsets handled by taps
    const int gx = x0 + tx, gy = y0 + ty, gz = z0 + tz;
    const bool valid = (gx < S) && (gy < S);
    const int pbase = ((gz + 1) * P + (gy + 1)) * P + (gx + 1);

    float acc[NCO];
    #pragma unroll
    for (int co = 0; co < NCO; ++co) acc[co] = b[co0 + co];

    float r0, r1, r2;
    auto load_raw = [&](int ci) {
        const float* ip = in + (size_t)ci * vol;
        r0 = ip[soff0];
        r1 = ip[soff1];
        r2 = (tid < 88) ? ip[soff2] : 0.0f;
    };
    auto xform_store = [&](int ci, int bsel) {
        float v0 = r0, v1 = r1, v2 = r2;
        if constexpr (NORM) {
            const float m = pst[ci * 2] * inv_n;
            float var = pst[ci * 2 + 1] * inv_n - m * m;
            const float rs = rsqrtf(fmaxf(var, 0.0f) + 1e-5f);
            v0 = (v0 - m) * rs; v0 = (v0 >= 0.0f) ? v0 : alpha * v0;
            v1 = (v1 - m) * rs; v1 = (v1 >= 0.0f) ? v1 : alpha * v1;
            v2 = (v2 - m) * rs; v2 = (v2 >= 0.0f) ? v2 : alpha * v2;
        }
        float* lb = lds[bsel];
        lb[tid] = v0 * ok0;
        lb[tid + 256] = v1 * ok1;
        if (tid < 88) lb[tid + 512] = v2 * ok2;
    };
    auto compute = [&](int ci, int bsel) {
        const float* lb = lds[bsel];
        float v[27];
        #pragma unroll
        for (int t = 0; t < 27; ++t)
            v[t] = lb[lbase + (t / 9) * 100 + ((t / 3) % 3) * 10 + (t % 3)];
        const float* wp = w + (size_t)(co0 * CIN + ci) * 27;
        #pragma unroll
        for (int co = 0; co < NCO; ++co)
            #pragma unroll
            for (int t = 0; t < 27; ++t)
                acc[co] = fmaf(v[t], wp[(size_t)co * CIN * 27 + t], acc[co]);
    };

    load_raw(0); xform_store(0, 0); __syncthreads();
    #pragma unroll 1
    for (int ci = 0; ci < CIN; ++ci) {
        if (ci + 1 < CIN) load_raw(ci + 1);          // in flight during compute
        compute(ci, ci & 1);
        if (ci + 1 < CIN) xform_store(ci + 1, (ci + 1) & 1);
        __syncthreads();
    }

    float* dbase = dst + head * HSTRIDE_P + (size_t)64 * cvol;
    #pragma unroll
    for (int co = 0; co < NCO; ++co) {
        float s1 = valid ? acc[co] : 0.0f;
        float s2 = valid ? acc[co] * acc[co] : 0.0f;
        #pragma unroll
        for (int off = 32; off; off >>= 1) {
            s1 += __shfl_xor(s1, off, 64);
            s2 += __shfl_xor(s2, off, 64);
        }
        if ((tid & 63) == 0) {
            float* st = stats + ((head * 4 + lvl) * 64 + co0 + co) * 2;
            atomicAdd(st + 0, s1);
            atomicAdd(st + 1, s2);
        }
        if (valid) dbase[(size_t)(co0 + co) * vol + pbase] = acc[co];
    }
}

// ---------------------------------------------------------------------------
// Final conv3d 64 -> {18 cls | 54 reg}, norm+PReLU fused into staging,
// channel-last into d_out.  Grid: (147, 4): y=0 cls; y=1..3 reg chunks.
// ---------------------------------------------------------------------------
__global__ __launch_bounds__(256) void final_conv_kernel(
    const float* __restrict__ src,
    const float* __restrict__ wf_cls, const float* __restrict__ bf_cls,
    const float* __restrict__ wf_reg, const float* __restrict__ bf_reg,
    const float* __restrict__ prev_stats,
    const float* __restrict__ a_cls, const float* __restrict__ a_reg,
    float* __restrict__ out)
{
    constexpr int NCO = 18;
    __shared__ float lds[2][HALO];
    const int tid  = threadIdx.x;
    const int yb   = blockIdx.y;
    const int head = (yb > 0) ? 1 : 0;
    const int co0  = head ? (yb - 1) * NCO : 0;
    const int OUT  = head ? 54 : 18;
    const float* wf = head ? wf_reg : wf_cls;
    const float* bf = head ? bf_reg : bf_cls;
    float* ob = out + (head ? CLS_TOTAL : 0);

    int lvl, S, P, vol, cvol, x0, y0, z0;
    decompose(blockIdx.x, lvl, S, P, vol, cvol, x0, y0, z0);
    const int loff = (lvl == 0) ? 0 : (lvl == 1) ? 32768 : (lvl == 2) ? 36864 : 37376;

    const float* in = src + head * HSTRIDE_P + (size_t)64 * cvol;
    const float alpha = (head ? a_reg : a_cls)[3];
    const float inv_n = 1.0f / (float)(1 << (3 * (5 - lvl)));
    const float* pst = prev_stats + (size_t)((head * 4 + lvl) * 64) * 2;

    int soff0, soff1, soff2; float ok0, ok1, ok2;
    {
        auto mk = [&](int i, int& so, float& ok) {
            const int zz = i / 100, rr = i - zz * 100, yy = rr / 10, xx = rr - yy * 10;
            so = ((z0 + zz) * P + (y0 + yy)) * P + (x0 + xx);
            const int gx = x0 + xx - 1, gy = y0 + yy - 1, gz = z0 + zz - 1;
            ok = ((unsigned)gx < (unsigned)S && (unsigned)gy < (unsigned)S &&
                  (unsigned)gz < (unsigned)S) ? 1.0f : 0.0f;
        };
        mk(tid, soff0, ok0);
        mk(tid + 256, soff1, ok1);
        mk(tid < 88 ? tid + 512 : 0, soff2, ok2);
        if (tid >= 88) ok2 = 0.0f;
    }

    const int tx = tid & 7, ty = (tid >> 3) & 7, tz = tid >> 6;
    const int lbase = (tz * 10 + ty) * 10 + tx;
    const int gx = x0 + tx, gy = y0 + ty, gz = z0 + tz;
    const bool valid = (gx < S) && (gy < S);

    float acc[NCO];
    #pragma unroll
    for (int co = 0; co < NCO; ++co) acc[co] = bf[co0 + co];

    float r0, r1, r2;
    auto load_raw = [&](int ci) {
        const float* ip = in + (size_t)ci * vol;
        r0 = ip[soff0];
        r1 = ip[soff1];
        r2 = (tid < 88) ? ip[soff2] : 0.0f;
    };
    auto xform_store = [&](int ci, int bsel) {
        const float m = pst[ci * 2] * inv_n;
        float var = pst[ci * 2 + 1] * inv_n - m * m;
        const float rs = rsqrtf(fmaxf(var, 0.0f) + 1e-5f);
        float v0 = (r0 - m) * rs; v0 = (v0 >= 0.0f) ? v0 : alpha * v0;
        float v1 = (r1 - m) * rs; v1 = (v1 >= 0.0f) ? v1 : alpha * v1;
        float v2 = (r2 - m) * rs; v2 = (v2 >= 0.0f) ? v2 : alpha * v2;
        float* lb = lds[bsel];
        lb[tid] = v0 * ok0;
        lb[tid + 256] = v1 * ok1;
        if (tid < 88) lb[tid + 512] = v2 * ok2;
    };
    auto compute = [&](int ci, int bsel) {
        const float* lb = lds[bsel];
        float v[27];
        #pragma unroll
        for (int t = 0; t < 27; ++t)
            v[t] = lb[lbase + (t / 9) * 100 + ((t / 3) % 3) * 10 + (t % 3)];
        const float* wp = wf + (size_t)(co0 * 64 + ci) * 27;
        #pragma unroll
        for (int co = 0; co < NCO; ++co)
            #pragma unroll
            for (int t = 0; t < 27; ++t)
                acc[co] = fmaf(v[t], wp[(size_t)co * 64 * 27 + t], acc[co]);
    };

    load_raw(0); xform_store(0, 0); __syncthreads();
    #pragma unroll 1
    for (int ci = 0; ci < 64; ++ci) {
        if (ci + 1 < 64) load_raw(ci + 1);
        compute(ci, ci & 1);
        if (ci + 1 < 64) xform_store(ci + 1, (ci + 1) & 1);
        __syncthreads();
    }

    if (valid) {
        const int voxel = (gz * S + gy) * S + gx;
        float* o = ob + (size_t)(loff + voxel) * OUT + co0;
        #pragma unroll
        for (int co = 0; co < NCO; ++co) o[co] = acc[co];
    }
}

// ---------------------------------------------------------------------------
extern "C" void kernel_launch(void* const* d_in, const int* in_sizes, int n_in,
                              void* d_out, int out_size, void* d_ws, size_t ws_size,
                              hipStream_t stream)
{
    const float* p0      = (const float*)d_in[0];
    const float* p1      = (const float*)d_in[1];
    const float* p2      = (const float*)d_in[2];
    const float* p3      = (const float*)d_in[3];
    const float* cls_w1  = (const float*)d_in[4];
    const float* cls_b1  = (const float*)d_in[5];
    const float* cls_w234= (const float*)d_in[6];
    const float* cls_b234= (const float*)d_in[7];
    const float* cls_a   = (const float*)d_in[8];
    const float* cls_wf  = (const float*)d_in[9];
    const float* cls_bf  = (const float*)d_in[10];
    const float* reg_w1  = (const float*)d_in[11];
    const float* reg_b1  = (const float*)d_in[12];
    const float* reg_w234= (const float*)d_in[13];
    const float* reg_b234= (const float*)d_in[14];
    const float* reg_a   = (const float*)d_in[15];
    const float* reg_wf  = (const float*)d_in[16];
    const float* reg_bf  = (const float*)d_in[17];

    float* ws    = (float*)d_ws;
    float* stats = ws;                        // 4 layers x 1024 floats
    float* padin = ws + 4096;                 // PADIN_SZ
    float* bufA  = padin + PADIN_SZ;          // 2 * HSTRIDE_P
    float* bufB  = bufA + 2 * HSTRIDE_P;      // 2 * HSTRIDE_P

    hipMemsetAsync(stats, 0, 4096 * sizeof(float), stream);
    padcopy_kernel<<<5265, 256, 0, stream>>>(p0, p1, p2, p3, padin);

    const dim3 cgrid(147, 2, 2);   // NCO=32

    // layer 0: 36 -> 64, raw input (no norm), padin shared (head_stride=0)
    conv_tile_kernel<36, 32, false><<<cgrid, 256, 0, stream>>>(
        padin, 0, cls_w1, reg_w1, cls_b1, reg_b1,
        nullptr, nullptr, nullptr, 0, bufA, stats);

    // layers 1..3: 64 -> 64, norm(prev stats)+PReLU fused into staging
    float* srcs[3] = { bufA, bufB, bufA };
    float* dsts[3] = { bufB, bufA, bufB };
    for (int l = 0; l < 3; ++l) {
        const float* wc = cls_w234 + (size_t)l * 64 * 64 * 27;
        const float* wr = reg_w234 + (size_t)l * 64 * 64 * 27;
        const float* bc = cls_b234 + l * 64;
        const float* br = reg_b234 + l * 64;
        conv_tile_kernel<64, 32, true><<<cgrid, 256, 0, stream>>>(
            srcs[l], HSTRIDE_P, wc, wr, bc, br,
            stats + l * 1024, cls_a, reg_a, l, dsts[l], stats + (l + 1) * 1024);
    }

    // final conv from bufB (raw layer-3 output): norm(stats3)+PReLU in staging
    final_conv_kernel<<<dim3(147, 4), 256, 0, stream>>>(
        bufB, cls_wf, cls_bf, reg_wf, reg_bf,
        stats + 3 * 1024, cls_a, reg_a, (float*)d_out);
}

// Round 5
// 909.874 us; speedup vs baseline: 7.0746x; 7.0746x over previous
//
#include <hip/hip_runtime.h>

// RetinaNet 3D head via bf16 MFMA implicit GEMM.
// 2 heads x 4 levels (S=32,16,8,4; vox 32768,4096,512,64; total 37440).
// Activations: zero-padded channel-last bf16 [pvox][64] (cin contiguous = K).
// Weights: bf16 [tap][cout][cin], cin/cout zero-padded to 64.
// Conv = 27 taps x 2 K-blocks of mfma_f32_16x16x32_bf16, fp32 accum.
// InstanceNorm+PReLU in a separate elementwise pass (stats fused into conv).

typedef __attribute__((ext_vector_type(8))) short short8;
typedef __attribute__((ext_vector_type(8))) unsigned short ushort8;
typedef __attribute__((ext_vector_type(4))) float f32x4;

static constexpr int TOTVOX   = 37440;
static constexpr int CLS_TOTAL = 673920;                 // 18 * 37440
static constexpr int TOTPADV  = 46352;                   // 39304+5832+1000+216
static constexpr size_t PAD_HSTRIDE_B = (size_t)TOTPADV * 64 * 2;   // bytes/head
static constexpr size_t WLAYER_E = 2u * 27 * 64 * 64;    // ushort elems per layer (both heads)

__device__ __forceinline__ unsigned short f2b(float x) {
    unsigned int u = __float_as_uint(x);
    u += 0x7FFFu + ((u >> 16) & 1u);
    return (unsigned short)(u >> 16);
}

__device__ __forceinline__ void voxdec(int vox, int& lvl, int& ls, int& loff,
                                       int& cvol, int& pbase)
{
    if (vox < 32768)      lvl = 0;
    else if (vox < 36864) lvl = 1;
    else if (vox < 37376) lvl = 2;
    else                  lvl = 3;
    ls = 5 - lvl;
    const int S = 1 << ls, P = S + 2;
    loff = (lvl == 0) ? 0 : (lvl == 1) ? 32768 : (lvl == 2) ? 36864 : 37376;
    cvol = (lvl == 0) ? 0 : (lvl == 1) ? 39304 : (lvl == 2) ? 45136 : 46136;
    const int v = vox - loff;
    const int x = v & (S - 1), y = (v >> ls) & (S - 1), z = v >> (2 * ls);
    pbase = ((z + 1) * P + (y + 1)) * P + (x + 1);
}

// ---------------------------------------------------------------------------
// Weight conversion: 5 layers x 2 heads -> bf16 [tap][cout(64)][cin(64)].
// dst[id] where id = ((s*2+head)*27 + t)*4096 + co*64 + ci. Grid 4320x256.
// ---------------------------------------------------------------------------
__global__ __launch_bounds__(256) void wconv_kernel(
    const float* __restrict__ cls_w1, const float* __restrict__ reg_w1,
    const float* __restrict__ cls_w234, const float* __restrict__ reg_w234,
    const float* __restrict__ cls_wf, const float* __restrict__ reg_wf,
    unsigned short* __restrict__ dst)
{
    const int id = blockIdx.x * 256 + (int)threadIdx.x;   // < 1,105,920
    const int s  = id / 221184;
    const int r  = id - s * 221184;
    const int head = r / 110592;
    const int r2 = r - head * 110592;
    const int t  = r2 >> 12;
    const int co = (r2 >> 6) & 63;
    const int ci = r2 & 63;

    float val = 0.0f;
    if (s == 0) {
        if (ci < 36) {
            const float* w = head ? reg_w1 : cls_w1;      // [64][36][27]
            val = w[(co * 36 + ci) * 27 + t];
        }
    } else if (s <= 3) {
        const float* w = (head ? reg_w234 : cls_w234) + (size_t)(s - 1) * 110592;
        val = w[(co * 64 + ci) * 27 + t];                 // [64][64][27]
    } else {
        const int OUT = head ? 54 : 18;
        if (co < OUT) {
            const float* w = head ? reg_wf : cls_wf;      // [OUT][64][27]
            val = w[(co * 64 + ci) * 27 + t];
        }
    }
    dst[id] = f2b(val);
}

// ---------------------------------------------------------------------------
// Input conversion: p0..p3 fp32 [36][nvox] -> padded bf16 [pvox][64] (ch>=36 =0).
// id = cbi*37440 + vox (cbi = channel-block 0..7). Grid 1170x256.
// ---------------------------------------------------------------------------
__global__ __launch_bounds__(256) void inconv_kernel(
    const float* __restrict__ p0, const float* __restrict__ p1,
    const float* __restrict__ p2, const float* __restrict__ p3,
    unsigned short* __restrict__ padin)
{
    const int id = blockIdx.x * 256 + (int)threadIdx.x;   // < 299,520
    const int cbi = id / 37440;
    const int vox = id - cbi * 37440;
    const int cb = cbi * 8;

    int lvl, ls, loff, cvol, pbase;
    voxdec(vox, lvl, ls, loff, cvol, pbase);
    const int nvox = 1 << (3 * ls);
    const int lvox = vox - loff;
    const float* src = (lvl == 0) ? p0 : (lvl == 1) ? p1 : (lvl == 2) ? p2 : p3;

    ushort8 o;
    #pragma unroll
    for (int j = 0; j < 8; ++j) {
        const int ch = cb + j;
        o[j] = (ch < 36) ? f2b(src[ch * nvox + lvox]) : (unsigned short)0;
    }
    *reinterpret_cast<ushort8*>(padin + ((size_t)(cvol + pbase) * 64 + cb)) = o;
}

// ---------------------------------------------------------------------------
// Conv layer: implicit GEMM with mfma_f32_16x16x32_bf16.
// Grid (585, 2 heads), block 256 = 4 waves; block tile 64 vox x 64 cout.
// Wave w: 64 vox x couts [w*16, w*16+16). No LDS, no barriers.
// ---------------------------------------------------------------------------
template<bool FINAL>
__global__ __launch_bounds__(256) void conv_mfma_kernel(
    const char* __restrict__ A, const size_t a_head_stride_b,
    const char* __restrict__ W,                     // layer base, bf16
    const float* __restrict__ b_cls, const float* __restrict__ b_reg,
    float* __restrict__ rawout, float* __restrict__ stats,
    float* __restrict__ dout)
{
    const int tid  = threadIdx.x;
    const int head = blockIdx.y;
    const int b    = blockIdx.x;

    int lvl, base;
    if (b < 512)      { lvl = 0; base = b * 64; }
    else if (b < 576) { lvl = 1; base = 32768 + (b - 512) * 64; }
    else if (b < 584) { lvl = 2; base = 36864 + (b - 576) * 64; }
    else              { lvl = 3; base = 37376; }
    const int ls = 5 - lvl, S = 1 << ls, P = S + 2;
    const int loff = (lvl == 0) ? 0 : (lvl == 1) ? 32768 : (lvl == 2) ? 36864 : 37376;
    const int cvol = (lvl == 0) ? 0 : (lvl == 1) ? 39304 : (lvl == 2) ? 45136 : 46136;
    const int lv = base - loff;

    const int lane = tid & 63, wv = tid >> 6;
    const int row = lane & 15, kg = lane >> 4;

    const char* Ab = A + (size_t)head * a_head_stride_b + (size_t)cvol * 128;
    const char* Wh = W + (size_t)head * (27 * 4096 * 2);

    int aoff[4];
    #pragma unroll
    for (int i = 0; i < 4; ++i) {
        const int v = lv + i * 16 + row;
        const int x = v & (S - 1), y = (v >> ls) & (S - 1), z = v >> (2 * ls);
        aoff[i] = (((z + 1) * P + (y + 1)) * P + (x + 1)) * 128 + kg * 16;
    }
    const int boff = ((wv * 16 + row) * 64 + kg * 8) * 2;

    f32x4 acc0 = {0.f,0.f,0.f,0.f}, acc1 = acc0, acc2 = acc0, acc3 = acc0;

    #pragma unroll 3
    for (int t = 0; t < 27; ++t) {
        const int dz = t / 9 - 1, dy = (t / 3) % 3 - 1, dx = t % 3 - 1;
        const int tb = ((dz * P + dy) * P + dx) * 128;
        const int wb = t * 8192;
        #pragma unroll
        for (int kb = 0; kb < 2; ++kb) {
            const int ab = tb + kb * 64;
            const short8 bw = *reinterpret_cast<const short8*>(Wh + boff + wb + kb * 64);
            const short8 a0 = *reinterpret_cast<const short8*>(Ab + aoff[0] + ab);
            const short8 a1 = *reinterpret_cast<const short8*>(Ab + aoff[1] + ab);
            const short8 a2 = *reinterpret_cast<const short8*>(Ab + aoff[2] + ab);
            const short8 a3 = *reinterpret_cast<const short8*>(Ab + aoff[3] + ab);
            acc0 = __builtin_amdgcn_mfma_f32_16x16x32_bf16(a0, bw, acc0, 0, 0, 0);
            acc1 = __builtin_amdgcn_mfma_f32_16x16x32_bf16(a1, bw, acc1, 0, 0, 0);
            acc2 = __builtin_amdgcn_mfma_f32_16x16x32_bf16(a2, bw, acc2, 0, 0, 0);
            acc3 = __builtin_amdgcn_mfma_f32_16x16x32_bf16(a3, bw, acc3, 0, 0, 0);
        }
    }

    const int cout = wv * 16 + row;
    const float bias = (head ? b_reg : b_cls)[cout];

    if constexpr (!FINAL) {
        float s1 = 0.f, s2 = 0.f;
        float* rp = rawout + (size_t)head * TOTVOX * 64;
        #pragma unroll
        for (int i = 0; i < 4; ++i) {
            const f32x4 a = (i == 0) ? acc0 : (i == 1) ? acc1 : (i == 2) ? acc2 : acc3;
            #pragma unroll
            for (int r = 0; r < 4; ++r) {
                const float val = a[r] + bias;
                const int vox = base + i * 16 + kg * 4 + r;
                rp[(size_t)vox * 64 + cout] = val;
                s1 += val; s2 += val * val;
            }
        }
        s1 += __shfl_xor(s1, 16, 64);
        s1 += __shfl_xor(s1, 32, 64);
        s2 += __shfl_xor(s2, 16, 64);
        s2 += __shfl_xor(s2, 32, 64);
        if (lane < 16) {
            float* st = stats + ((head * 4 + lvl) * 64 + wv * 16 + lane) * 2;
            atomicAdd(st + 0, s1);
            atomicAdd(st + 1, s2);
        }
    } else {
        const int OUT = head ? 54 : 18;
        float* ob = dout + (head ? CLS_TOTAL : 0);
        if (cout < OUT) {
            #pragma unroll
            for (int i = 0; i < 4; ++i) {
                const f32x4 a = (i == 0) ? acc0 : (i == 1) ? acc1 : (i == 2) ? acc2 : acc3;
                #pragma unroll
                for (int r = 0; r < 4; ++r) {
                    const int vox = base + i * 16 + kg * 4 + r;
                    ob[(size_t)vox * OUT + cout] = a[r] + bias;
                }
            }
        }
    }
}

// ---------------------------------------------------------------------------
// InstanceNorm + PReLU + bf16-convert: raw fp32 [head][vox][64] -> padded
// bf16 [head][pvox][64]. id = head*299520 + vox*8 + cbi. Grid 2340x256.
// ---------------------------------------------------------------------------
__global__ __launch_bounds__(256) void norm_kernel(
    const float* __restrict__ raw, const float* __restrict__ stats,
    const float* __restrict__ a_cls, const float* __restrict__ a_reg,
    const int layer, unsigned short* __restrict__ pad)
{
    const int id = blockIdx.x * 256 + (int)threadIdx.x;   // < 599,040
    const int head = id >= 299520;
    const int e = id - head * 299520;
    const int vox = e >> 3;
    const int cb = (e & 7) << 3;

    int lvl, ls, loff, cvol, pbase;
    voxdec(vox, lvl, ls, loff, cvol, pbase);
    const float inv_n = 1.0f / (float)(1 << (3 * ls));
    const float alpha = (head ? a_reg : a_cls)[layer];

    const float* rp = raw + ((size_t)head * TOTVOX + vox) * 64 + cb;
    const float* st = stats + ((head * 4 + lvl) * 64 + cb) * 2;

    ushort8 o;
    #pragma unroll
    for (int j = 0; j < 8; ++j) {
        const float m = st[2 * j] * inv_n;
        float var = st[2 * j + 1] * inv_n - m * m;
        const float rs = rsqrtf(fmaxf(var, 0.0f) + 1e-5f);
        float v = (rp[j] - m) * rs;
        v = (v >= 0.0f) ? v : alpha * v;
        o[j] = f2b(v);
    }
    unsigned short* dp = pad + (size_t)head * TOTPADV * 64
                             + (size_t)(cvol + pbase) * 64 + cb;
    *reinterpret_cast<ushort8*>(dp) = o;
}

// ---------------------------------------------------------------------------
extern "C" void kernel_launch(void* const* d_in, const int* in_sizes, int n_in,
                              void* d_out, int out_size, void* d_ws, size_t ws_size,
                              hipStream_t stream)
{
    const float* p0      = (const float*)d_in[0];
    const float* p1      = (const float*)d_in[1];
    const float* p2      = (const float*)d_in[2];
    const float* p3      = (const float*)d_in[3];
    const float* cls_w1  = (const float*)d_in[4];
    const float* cls_b1  = (const float*)d_in[5];
    const float* cls_w234= (const float*)d_in[6];
    const float* cls_b234= (const float*)d_in[7];
    const float* cls_a   = (const float*)d_in[8];
    const float* cls_wf  = (const float*)d_in[9];
    const float* cls_bf  = (const float*)d_in[10];
    const float* reg_w1  = (const float*)d_in[11];
    const float* reg_b1  = (const float*)d_in[12];
    const float* reg_w234= (const float*)d_in[13];
    const float* reg_b234= (const float*)d_in[14];
    const float* reg_a   = (const float*)d_in[15];
    const float* reg_wf  = (const float*)d_in[16];
    const float* reg_bf  = (const float*)d_in[17];

    char* ws = (char*)d_ws;
    // layout (bytes):
    float*          stats  = (float*)ws;                         // 16384
    unsigned short* padIn0 = (unsigned short*)(ws + 16384);      // 5,933,056
    unsigned short* padA   = (unsigned short*)(ws + 5949440);    // 11,866,112
    unsigned short* padB   = (unsigned short*)(ws + 17815552);   // 11,866,112
    float*          rawout = (float*)(ws + 29681664);            // 19,169,280
    unsigned short* wcvt   = (unsigned short*)(ws + 48850944);   // 2,211,840

    // zero stats + all padded activation buffers (pads must be 0)
    hipMemsetAsync(ws, 0, 29681664, stream);

    wconv_kernel<<<4320, 256, 0, stream>>>(
        cls_w1, reg_w1, cls_w234, reg_w234, cls_wf, reg_wf, wcvt);
    inconv_kernel<<<1170, 256, 0, stream>>>(p0, p1, p2, p3, padIn0);

    const dim3 cgrid(585, 2);

    // layer 0: padIn0 (shared heads: stride 0)
    conv_mfma_kernel<false><<<cgrid, 256, 0, stream>>>(
        (const char*)padIn0, 0, (const char*)wcvt,
        cls_b1, reg_b1, rawout, stats, nullptr);
    norm_kernel<<<2340, 256, 0, stream>>>(rawout, stats, cls_a, reg_a, 0, padA);

    // layers 1..3: padA -> padB -> padA -> padB
    unsigned short* srcs[3] = { padA, padB, padA };
    unsigned short* dsts[3] = { padB, padA, padB };
    for (int l = 0; l < 3; ++l) {
        conv_mfma_kernel<false><<<cgrid, 256, 0, stream>>>(
            (const char*)srcs[l], PAD_HSTRIDE_B,
            (const char*)(wcvt + (size_t)(l + 1) * WLAYER_E),
            cls_b234 + l * 64, reg_b234 + l * 64,
            rawout, stats + (l + 1) * 1024, nullptr);
        norm_kernel<<<2340, 256, 0, stream>>>(
            rawout, stats + (l + 1) * 1024, cls_a, reg_a, l + 1, dsts[l]);
    }

    // final conv: padB -> d_out (channel-last, cls then reg)
    conv_mfma_kernel<true><<<cgrid, 256, 0, stream>>>(
        (const char*)padB, PAD_HSTRIDE_B,
        (const char*)(wcvt + 4 * WLAYER_E),
        cls_bf, reg_bf, nullptr, nullptr, (float*)d_out);
}